// Round 4
// baseline (545.683 us; speedup 1.0000x reference)
//
#include <hip/hip_runtime.h>
#include <hip/hip_bf16.h>

#define BATCH 4096
#define NEXP  16
#define DIN   2048
#define DOUT  2048

#define BM 128
#define BN 128
#define BK 32   // fp32 k per tile; LDS row = 64 bf16 = [hi(32) | lo(32)]

typedef __attribute__((ext_vector_type(4))) float f32x4;
typedef __attribute__((ext_vector_type(8))) short bf16x8;

// --- Kernel 1: bucket sample indices by expert; write mxs/actions tail ---
__global__ void sort_kernel(const int* __restrict__ actions,
                            const float* __restrict__ mxs,
                            float* __restrict__ out_tail,   // d_out + BATCH*DOUT
                            int* __restrict__ offs,         // [NEXP+1]
                            int* __restrict__ sorted) {     // [BATCH]
    __shared__ int s_cnt[NEXP];
    __shared__ int s_cur[NEXP];
    const int tid = threadIdx.x;
    if (tid < NEXP) s_cnt[tid] = 0;
    __syncthreads();
    for (int i = tid; i < BATCH; i += blockDim.x) {
        int a = actions[i];
        atomicAdd(&s_cnt[a], 1);
        out_tail[i] = mxs[i];                    // mxs pass-through
        out_tail[BATCH + i] = (float)a;          // actions pass-through
    }
    __syncthreads();
    if (tid == 0) {
        int run = 0;
        for (int e = 0; e < NEXP; ++e) {
            offs[e] = run;
            s_cur[e] = run;
            run += s_cnt[e];
        }
        offs[NEXP] = run;
    }
    __syncthreads();
    // Bucket order is atomics-dependent, but each sample's output row is
    // computed independently (k-loop order fixed) -> output bit-deterministic.
    for (int i = tid; i < BATCH; i += blockDim.x) {
        int e = actions[i];
        int pos = atomicAdd(&s_cur[e], 1);
        sorted[pos] = i;
    }
}

// Split fp32 pair -> packed bf16 hi (bit-truncate) + bf16 lo (exact residual).
__device__ __forceinline__ void split_pair(float x0, float x1, unsigned& h, unsigned& l) {
    unsigned b0 = __float_as_uint(x0), b1 = __float_as_uint(x1);
    unsigned h0 = b0 & 0xFFFF0000u;
    unsigned h1 = b1 & 0xFFFF0000u;
    h = h1 | (b0 >> 16);
    unsigned l0 = __float_as_uint(x0 - __uint_as_float(h0));
    unsigned l1 = __float_as_uint(x1 - __uint_as_float(h1));
    l = (l1 & 0xFFFF0000u) | (l0 >> 16);
}

__device__ __forceinline__ void split_f4pair(float4 a, float4 b, uint4& h, uint4& l) {
    split_pair(a.x, a.y, h.x, l.x);
    split_pair(a.z, a.w, h.y, l.y);
    split_pair(b.x, b.y, h.z, l.z);
    split_pair(b.z, b.w, h.w, l.w);
}

// LDS element index for row r, 16B block kb (0..7; 0-3 hi, 4-7 lo), XOR-swizzled.
// Verified 0 bank conflicts in round-3 bench with the same structure.
__device__ __forceinline__ int lidx(int r, int kb) {
    return r * 64 + ((kb ^ (r & 7)) << 3);
}

// --- Kernel 2: grouped gather-GEMM, split-bf16 3-product MFMA ---
// grid = (DOUT/BN, NEXP, BATCH/BM); block = 256 (4 waves, 2x2 of 64x64)
__global__ __launch_bounds__(256, 4)
void gemm_kernel(const float* __restrict__ xs,
                 const float* __restrict__ W,
                 const float* __restrict__ bias,
                 const int* __restrict__ offs,
                 const int* __restrict__ sorted,
                 float* __restrict__ out) {
    __shared__ __align__(16) unsigned short Xs[BM * 64];   // 16 KB
    __shared__ __align__(16) unsigned short Ws[BN * 64];   // 16 KB

    const int e = blockIdx.y;
    const int start = offs[e];
    const int cnt = offs[e + 1] - start;
    const int m0 = blockIdx.z * BM;
    if (m0 >= cnt) return;
    const int n0 = blockIdx.x * BN;

    const int tid = threadIdx.x;
    const int lane = tid & 63;
    const int wave = tid >> 6;
    const int wm = wave >> 1;      // wave row (0..1), 64 output rows each
    const int wn = wave & 1;       // wave col (0..1), 64 output cols each

    // Staging role: one row per thread-half, 16-float chunk kq.
    const int srow = tid & 127;    // 0..127
    const int kq = tid >> 7;       // 0..1  (floats kq*16 .. kq*16+15)

    const int rm_s = m0 + srow;
    const int xrow = (rm_s < cnt) ? sorted[start + rm_s] : -1;
    const float* xsrc = xs + (size_t)(xrow < 0 ? 0 : xrow) * DIN + kq * 16;
    const float* wsrc = W + ((size_t)e * DOUT + n0 + srow) * DIN + kq * 16;

    f32x4 acc[4][4];
#pragma unroll
    for (int i = 0; i < 4; ++i)
#pragma unroll
        for (int j = 0; j < 4; ++j) acc[i][j] = (f32x4){0.f, 0.f, 0.f, 0.f};

    // ---- prologue: load tile 0 into regs ----
    float4 px[4], pw[4];
#pragma unroll
    for (int j = 0; j < 4; ++j) {
        px[j] = (xrow >= 0) ? *(const float4*)(xsrc + j * 4)
                            : make_float4(0.f, 0.f, 0.f, 0.f);
        pw[j] = *(const float4*)(wsrc + j * 4);
    }

    for (int k0 = 0; k0 < DIN; k0 += BK) {
        // ---- phase 1: convert prefetched regs -> LDS (hi|lo packed) ----
        uint4 xh0, xl0, xh1, xl1, wh0, wl0, wh1, wl1;
        split_f4pair(px[0], px[1], xh0, xl0);
        split_f4pair(px[2], px[3], xh1, xl1);
        split_f4pair(pw[0], pw[1], wh0, wl0);
        split_f4pair(pw[2], pw[3], wh1, wl1);
        *(uint4*)&Xs[lidx(srow, 2 * kq)]     = xh0;
        *(uint4*)&Xs[lidx(srow, 2 * kq + 1)] = xh1;
        *(uint4*)&Xs[lidx(srow, 4 + 2 * kq)]     = xl0;
        *(uint4*)&Xs[lidx(srow, 4 + 2 * kq + 1)] = xl1;
        *(uint4*)&Ws[lidx(srow, 2 * kq)]     = wh0;
        *(uint4*)&Ws[lidx(srow, 2 * kq + 1)] = wh1;
        *(uint4*)&Ws[lidx(srow, 4 + 2 * kq)]     = wl0;
        *(uint4*)&Ws[lidx(srow, 4 + 2 * kq + 1)] = wl1;
        __syncthreads();

        // ---- phase 2a: issue next-tile global loads (land during MFMA) ----
        {
            int kn = (k0 + BK < DIN) ? (k0 + BK) : 0;   // last iter: harmless reload
#pragma unroll
            for (int j = 0; j < 4; ++j) {
                px[j] = (xrow >= 0) ? *(const float4*)(xsrc + kn + j * 4)
                                    : make_float4(0.f, 0.f, 0.f, 0.f);
                pw[j] = *(const float4*)(wsrc + kn + j * 4);
            }
        }

        // ---- phase 2b: fragments + 48 MFMA ----
        {
            const int g = lane >> 4;     // k-group 0..3
            const int rl = lane & 15;    // row-in-fragment
            bf16x8 ah[4], al[4];
#pragma unroll
            for (int mi = 0; mi < 4; ++mi) {
                int R = wm * 64 + mi * 16 + rl;
                ah[mi] = *(const bf16x8*)&Xs[lidx(R, g)];
                al[mi] = *(const bf16x8*)&Xs[lidx(R, 4 + g)];
            }
#pragma unroll
            for (int ni = 0; ni < 4; ++ni) {
                int R = wn * 64 + ni * 16 + rl;
                bf16x8 bh = *(const bf16x8*)&Ws[lidx(R, g)];
                bf16x8 bl = *(const bf16x8*)&Ws[lidx(R, 4 + g)];
#pragma unroll
                for (int mi = 0; mi < 4; ++mi) {
                    acc[mi][ni] = __builtin_amdgcn_mfma_f32_16x16x32_bf16(ah[mi], bh, acc[mi][ni], 0, 0, 0);
                    acc[mi][ni] = __builtin_amdgcn_mfma_f32_16x16x32_bf16(ah[mi], bl, acc[mi][ni], 0, 0, 0);
                    acc[mi][ni] = __builtin_amdgcn_mfma_f32_16x16x32_bf16(al[mi], bh, acc[mi][ni], 0, 0, 0);
                }
            }
        }
        __syncthreads();
    }

    // ---- epilogue: bias add + scatter rows ----
    const int g = lane >> 4, rl = lane & 15;
    float bv[4];
#pragma unroll
    for (int ni = 0; ni < 4; ++ni)
        bv[ni] = bias[(size_t)e * DOUT + n0 + wn * 64 + ni * 16 + rl];
#pragma unroll
    for (int mi = 0; mi < 4; ++mi) {
#pragma unroll
        for (int j = 0; j < 4; ++j) {
            int rm = m0 + wm * 64 + mi * 16 + g * 4 + j;
            if (rm < cnt) {
                int s = sorted[start + rm];
                float* orow = out + (size_t)s * DOUT + n0 + wn * 64 + rl;
#pragma unroll
                for (int ni = 0; ni < 4; ++ni)
                    orow[ni * 16] = acc[mi][ni][j] + bv[ni];
            }
        }
    }
}

extern "C" void kernel_launch(void* const* d_in, const int* in_sizes, int n_in,
                              void* d_out, int out_size, void* d_ws, size_t ws_size,
                              hipStream_t stream) {
    const float* xs      = (const float*)d_in[0];
    const float* mxs     = (const float*)d_in[1];
    const int*   actions = (const int*)d_in[2];
    const float* W       = (const float*)d_in[3];
    const float* b       = (const float*)d_in[4];
    float* out = (float*)d_out;

    int* ws_i   = (int*)d_ws;
    int* offs   = ws_i;         // NEXP+1
    int* sorted = ws_i + 32;    // BATCH

    sort_kernel<<<1, 1024, 0, stream>>>(actions, mxs,
                                        out + (size_t)BATCH * DOUT, offs, sorted);

    dim3 grid(DOUT / BN, NEXP, BATCH / BM);
    gemm_kernel<<<grid, 256, 0, stream>>>(xs, W, b, offs, sorted, out);
}

// Round 5
// 376.715 us; speedup vs baseline: 1.4485x; 1.4485x over previous
//
#include <hip/hip_runtime.h>
#include <hip/hip_bf16.h>

#define BATCH 4096
#define NEXP  16
#define DIN   2048
#define DOUT  2048

#define BM 128
#define BN 64
#define BK 32   // fp32 k per tile; LDS row = 64 bf16 = [hi(32) | lo(32)]

typedef __attribute__((ext_vector_type(4))) float f32x4;
typedef __attribute__((ext_vector_type(8))) short bf16x8;

// --- Kernel 1: bucket sample indices by expert; write mxs/actions tail ---
__global__ void sort_kernel(const int* __restrict__ actions,
                            const float* __restrict__ mxs,
                            float* __restrict__ out_tail,   // d_out + BATCH*DOUT
                            int* __restrict__ offs,         // [NEXP+1]
                            int* __restrict__ sorted) {     // [BATCH]
    __shared__ int s_cnt[NEXP];
    __shared__ int s_cur[NEXP];
    const int tid = threadIdx.x;
    if (tid < NEXP) s_cnt[tid] = 0;
    __syncthreads();
    for (int i = tid; i < BATCH; i += blockDim.x) {
        int a = actions[i];
        atomicAdd(&s_cnt[a], 1);
        out_tail[i] = mxs[i];                    // mxs pass-through
        out_tail[BATCH + i] = (float)a;          // actions pass-through
    }
    __syncthreads();
    if (tid == 0) {
        int run = 0;
        for (int e = 0; e < NEXP; ++e) {
            offs[e] = run;
            s_cur[e] = run;
            run += s_cnt[e];
        }
        offs[NEXP] = run;
    }
    __syncthreads();
    // Bucket order is atomics-dependent, but each sample's output row is
    // computed independently (k-loop order fixed) -> output bit-deterministic.
    for (int i = tid; i < BATCH; i += blockDim.x) {
        int e = actions[i];
        int pos = atomicAdd(&s_cur[e], 1);
        sorted[pos] = i;
    }
}

// Split fp32 pair -> packed bf16 hi (bit-truncate) + bf16 lo (exact residual).
__device__ __forceinline__ void split_pair(float x0, float x1, unsigned& h, unsigned& l) {
    unsigned b0 = __float_as_uint(x0), b1 = __float_as_uint(x1);
    unsigned h0 = b0 & 0xFFFF0000u;
    unsigned h1 = b1 & 0xFFFF0000u;
    h = h1 | (b0 >> 16);
    unsigned l0 = __float_as_uint(x0 - __uint_as_float(h0));
    unsigned l1 = __float_as_uint(x1 - __uint_as_float(h1));
    l = (l1 & 0xFFFF0000u) | (l0 >> 16);
}

__device__ __forceinline__ void split_f4pair(float4 a, float4 b, uint4& h, uint4& l) {
    split_pair(a.x, a.y, h.x, l.x);
    split_pair(a.z, a.w, h.y, l.y);
    split_pair(b.x, b.y, h.z, l.z);
    split_pair(b.z, b.w, h.w, l.w);
}

// LDS element index: row r (stride 64 bf16 = 128B), 16B block kb (0..7;
// 0-3 hi, 4-7 lo), XOR-swizzled. Measured 0 bank conflicts (rounds 3,4).
__device__ __forceinline__ int lidx(int r, int kb) {
    return r * 64 + ((kb ^ (r & 7)) << 3);
}

// --- Kernel 2: grouped gather-GEMM, split-bf16 3-product MFMA ---
// grid = (DOUT/BN=32, NEXP, BATCH/BM=32); block = 256 (4 waves, 2x2; wave tile 64x32)
__global__ __launch_bounds__(256, 3)
void gemm_kernel(const float* __restrict__ xs,
                 const float* __restrict__ W,
                 const float* __restrict__ bias,
                 const int* __restrict__ offs,
                 const int* __restrict__ sorted,
                 float* __restrict__ out) {
    __shared__ __align__(16) unsigned short Xs[BM * 64];   // 16 KB
    __shared__ __align__(16) unsigned short Ws[BN * 64];   // 8 KB

    const int e = blockIdx.y;
    const int start = offs[e];
    const int cnt = offs[e + 1] - start;
    const int m0 = blockIdx.z * BM;
    if (m0 >= cnt) return;
    const int n0 = blockIdx.x * BN;

    const int tid = threadIdx.x;
    const int lane = tid & 63;
    const int wave = tid >> 6;
    const int wm = wave >> 1;      // 0..1: rows wm*64 .. +63
    const int wn = wave & 1;       // 0..1: cols wn*32 .. +31

    // X staging: row srow (0..127), 16-float chunk kq (0..1)
    const int srow = tid & 127;
    const int kq = tid >> 7;
    // W staging: row swr (0..63), 8-float chunk wkq (0..3)
    const int swr = tid >> 2;
    const int wkq = tid & 3;

    const int rm_s = m0 + srow;
    const int xrow = (rm_s < cnt) ? sorted[start + rm_s] : -1;
    const float* xsrc = xs + (size_t)(xrow < 0 ? 0 : xrow) * DIN + kq * 16;
    const float* wsrc = W + ((size_t)e * DOUT + n0 + swr) * DIN + wkq * 8;

    f32x4 acc[4][2];
#pragma unroll
    for (int i = 0; i < 4; ++i)
#pragma unroll
        for (int j = 0; j < 2; ++j) acc[i][j] = (f32x4){0.f, 0.f, 0.f, 0.f};

    // ---- prologue: load tile 0 into regs ----
    float4 px[4], pw[2];
#pragma unroll
    for (int j = 0; j < 4; ++j)
        px[j] = (xrow >= 0) ? *(const float4*)(xsrc + j * 4)
                            : make_float4(0.f, 0.f, 0.f, 0.f);
    pw[0] = *(const float4*)(wsrc);
    pw[1] = *(const float4*)(wsrc + 4);

    for (int k0 = 0; k0 < DIN; k0 += BK) {
        // ---- phase 1: convert prefetched regs -> LDS (hi|lo packed) ----
        {
            uint4 xh0, xl0, xh1, xl1, wh, wl;
            split_f4pair(px[0], px[1], xh0, xl0);
            split_f4pair(px[2], px[3], xh1, xl1);
            split_f4pair(pw[0], pw[1], wh, wl);
            *(uint4*)&Xs[lidx(srow, 2 * kq)]         = xh0;
            *(uint4*)&Xs[lidx(srow, 2 * kq + 1)]     = xh1;
            *(uint4*)&Xs[lidx(srow, 4 + 2 * kq)]     = xl0;
            *(uint4*)&Xs[lidx(srow, 4 + 2 * kq + 1)] = xl1;
            *(uint4*)&Ws[lidx(swr, wkq)]             = wh;
            *(uint4*)&Ws[lidx(swr, 4 + wkq)]         = wl;
        }
        __syncthreads();

        // ---- phase 2a: issue next-tile global loads (land during MFMA) ----
        {
            int kn = (k0 + BK < DIN) ? (k0 + BK) : 0;   // last iter: harmless reload
#pragma unroll
            for (int j = 0; j < 4; ++j)
                px[j] = (xrow >= 0) ? *(const float4*)(xsrc + kn + j * 4)
                                    : make_float4(0.f, 0.f, 0.f, 0.f);
            pw[0] = *(const float4*)(wsrc + kn);
            pw[1] = *(const float4*)(wsrc + kn + 4);
        }

        // ---- phase 2b: fragments + 24 MFMA (product-major: dep distance 8) ----
        {
            const int g = lane >> 4;     // k-group 0..3
            const int rl = lane & 15;    // row-in-fragment
            bf16x8 ah[4], al[4], bh[2], bl[2];
#pragma unroll
            for (int mi = 0; mi < 4; ++mi) {
                int R = wm * 64 + mi * 16 + rl;
                ah[mi] = *(const bf16x8*)&Xs[lidx(R, g)];
                al[mi] = *(const bf16x8*)&Xs[lidx(R, 4 + g)];
            }
#pragma unroll
            for (int ni = 0; ni < 2; ++ni) {
                int R = wn * 32 + ni * 16 + rl;
                bh[ni] = *(const bf16x8*)&Ws[lidx(R, g)];
                bl[ni] = *(const bf16x8*)&Ws[lidx(R, 4 + g)];
            }
#pragma unroll
            for (int mi = 0; mi < 4; ++mi)
#pragma unroll
                for (int ni = 0; ni < 2; ++ni)
                    acc[mi][ni] = __builtin_amdgcn_mfma_f32_16x16x32_bf16(ah[mi], bh[ni], acc[mi][ni], 0, 0, 0);
#pragma unroll
            for (int mi = 0; mi < 4; ++mi)
#pragma unroll
                for (int ni = 0; ni < 2; ++ni)
                    acc[mi][ni] = __builtin_amdgcn_mfma_f32_16x16x32_bf16(ah[mi], bl[ni], acc[mi][ni], 0, 0, 0);
#pragma unroll
            for (int mi = 0; mi < 4; ++mi)
#pragma unroll
                for (int ni = 0; ni < 2; ++ni)
                    acc[mi][ni] = __builtin_amdgcn_mfma_f32_16x16x32_bf16(al[mi], bh[ni], acc[mi][ni], 0, 0, 0);
        }
        __syncthreads();
    }

    // ---- epilogue: bias add + scatter rows ----
    const int g = lane >> 4, rl = lane & 15;
    float bv[2];
#pragma unroll
    for (int ni = 0; ni < 2; ++ni)
        bv[ni] = bias[(size_t)e * DOUT + n0 + wn * 32 + ni * 16 + rl];
#pragma unroll
    for (int mi = 0; mi < 4; ++mi) {
#pragma unroll
        for (int j = 0; j < 4; ++j) {
            int rm = m0 + wm * 64 + mi * 16 + g * 4 + j;
            if (rm < cnt) {
                int s = sorted[start + rm];
                float* orow = out + (size_t)s * DOUT + n0 + wn * 32 + rl;
#pragma unroll
                for (int ni = 0; ni < 2; ++ni)
                    orow[ni * 16] = acc[mi][ni][j] + bv[ni];
            }
        }
    }
}

extern "C" void kernel_launch(void* const* d_in, const int* in_sizes, int n_in,
                              void* d_out, int out_size, void* d_ws, size_t ws_size,
                              hipStream_t stream) {
    const float* xs      = (const float*)d_in[0];
    const float* mxs     = (const float*)d_in[1];
    const int*   actions = (const int*)d_in[2];
    const float* W       = (const float*)d_in[3];
    const float* b       = (const float*)d_in[4];
    float* out = (float*)d_out;

    int* ws_i   = (int*)d_ws;
    int* offs   = ws_i;         // NEXP+1
    int* sorted = ws_i + 32;    // BATCH

    sort_kernel<<<1, 1024, 0, stream>>>(actions, mxs,
                                        out + (size_t)BATCH * DOUT, offs, sorted);

    dim3 grid(DOUT / BN, NEXP, BATCH / BM);
    gemm_kernel<<<grid, 256, 0, stream>>>(xs, W, b, offs, sorted, out);
}

// Round 7
// 270.886 us; speedup vs baseline: 2.0144x; 1.3907x over previous
//
#include <hip/hip_runtime.h>
#include <hip/hip_bf16.h>

#define BATCH 4096
#define NEXP  16
#define DIN   2048
#define DOUT  2048

#define BM 128
#define BN 128
#define NKT 64            // 64 k-tiles of 32 fp32 each

#define WS_X_OFF  65536
#define WS_X_BYTES ((size_t)BATCH * 8192)   // 4096 rows x 64 kt x 128 B

typedef __attribute__((ext_vector_type(4))) float f32x4;
typedef __attribute__((ext_vector_type(8))) short bf16x8;

// --- Kernel 1: bucket sample indices by expert; write mxs/actions tail ---
__global__ void sort_kernel(const int* __restrict__ actions,
                            const float* __restrict__ mxs,
                            float* __restrict__ out_tail,
                            int* __restrict__ offs,
                            int* __restrict__ sorted) {
    __shared__ int s_cnt[NEXP];
    __shared__ int s_cur[NEXP];
    const int tid = threadIdx.x;
    if (tid < NEXP) s_cnt[tid] = 0;
    __syncthreads();
    for (int i = tid; i < BATCH; i += blockDim.x) {
        int a = actions[i];
        atomicAdd(&s_cnt[a], 1);
        out_tail[i] = mxs[i];
        out_tail[BATCH + i] = (float)a;
    }
    __syncthreads();
    if (tid == 0) {
        int run = 0;
        for (int e = 0; e < NEXP; ++e) { offs[e] = run; s_cur[e] = run; run += s_cnt[e]; }
        offs[NEXP] = run;
    }
    __syncthreads();
    // Bucket order is atomics-dependent, but each sample's output is computed
    // independently with fixed k-order -> output bit-deterministic.
    for (int i = tid; i < BATCH; i += blockDim.x) {
        int e = actions[i];
        int pos = atomicAdd(&s_cur[e], 1);
        sorted[pos] = i;
    }
}

// Split fp32 pair -> packed bf16 hi (bit-truncate) + bf16 lo (exact residual).
__device__ __forceinline__ void split_pair(float x0, float x1, unsigned& h, unsigned& l) {
    unsigned b0 = __float_as_uint(x0), b1 = __float_as_uint(x1);
    unsigned h0 = b0 & 0xFFFF0000u;
    unsigned h1 = b1 & 0xFFFF0000u;
    h = h1 | (b0 >> 16);
    unsigned l0 = __float_as_uint(x0 - __uint_as_float(h0));
    unsigned l1 = __float_as_uint(x1 - __uint_as_float(h1));
    l = (l1 & 0xFFFF0000u) | (l0 >> 16);
}

__device__ __forceinline__ void split_f4pair(float4 a, float4 b, uint4& h, uint4& l) {
    split_pair(a.x, a.y, h.x, l.x);
    split_pair(a.z, a.w, h.y, l.y);
    split_pair(b.x, b.y, h.z, l.z);
    split_pair(b.z, b.w, h.w, l.w);
}

// LDS element index: row r (128 B row = 8 x 16B blocks; logical 0-3 hi, 4-7 lo),
// physical block = kb ^ (r&7). Read pattern measured conflict-free (r3/r5).
__device__ __forceinline__ int lidx(int r, int kb) {
    return r * 64 + ((kb ^ (r & 7)) << 3);
}

// --- Kernel 1b: pre-split X into ws, gathered by sorted position ---
// Swizzle key = EXPERT-LOCAL position & 7 (r6 bug: was global rm&7, which
// mismatches the GEMM's LDS-row key when offs[e] % 8 != 0).
__global__ void xsplit_kernel(const float* __restrict__ xs,
                              const int* __restrict__ sorted,
                              const int* __restrict__ offs,
                              const int* __restrict__ actions,
                              unsigned char* __restrict__ xws) {
    const int rm = blockIdx.x * 4 + (threadIdx.x >> 6);
    const int l  = threadIdx.x & 63;        // kt chunk index
    const int src = sorted[rm];
    const int e = actions[src];
    const int local = rm - offs[e];         // expert-local sorted position
    const float* s = xs + (size_t)src * DIN + l * 32;
    uint4 blk[8];
#pragma unroll
    for (int c = 0; c < 4; ++c) {
        float4 a = *(const float4*)(s + c * 8);
        float4 b = *(const float4*)(s + c * 8 + 4);
        uint4 h, lo;
        split_f4pair(a, b, h, lo);
        blk[c] = h; blk[4 + c] = lo;
    }
    uint4* dst = (uint4*)(xws + (size_t)rm * 8192 + (size_t)l * 128);
    const int key = local & 7;
#pragma unroll
    for (int p = 0; p < 8; ++p)
        dst[p] = blk[p ^ key];
}

// --- Kernel 2: grouped GEMM; X via global_load_lds (dbuf, counted vmcnt),
//     W converted in-reg (2-deep prefetch), 3-product split-bf16 MFMA ---
// grid = (16, NEXP, 32); block 256 (2x2 waves, wave tile 64x64)
__global__ __launch_bounds__(256, 2)
void gemm_kernel(const unsigned char* __restrict__ xws,
                 const float* __restrict__ W,
                 const float* __restrict__ bias,
                 const int* __restrict__ offs,
                 const int* __restrict__ sorted,
                 float* __restrict__ out) {
    __shared__ __align__(16) unsigned short Xs[2][BM * 64];  // 2 x 16 KB
    __shared__ __align__(16) unsigned short Wl[BN * 64];     // 16 KB

    const int e = blockIdx.y;
    const int start = offs[e];
    const int cnt = offs[e + 1] - start;
    const int m0 = blockIdx.z * BM;
    if (m0 >= cnt) return;
    const int n0 = blockIdx.x * BN;

    const int tid = threadIdx.x;
    const int lane = tid & 63;
    const int wave = tid >> 6;
    const int wm = wave >> 1, wn = wave & 1;
    const int g = lane >> 4, rl = lane & 15;

    // W staging: row swr (0..127), 16-float chunk wc (0..1) — the r3/r5 X
    // pattern (measured 0 bank conflicts).
    const int swr = tid & 127;
    const int wc = tid >> 7;
    const float* wsrc = W + ((size_t)e * DOUT + n0 + swr) * DIN + wc * 16;

    // X gload source rows: GLOBAL sorted position = start + m0 + local row
    // (r6 bug: 'start' was missing). Clamp to BATCH-1: rows >= cnt load
    // garbage that the epilogue never writes, but stay in-bounds of xws.
    const unsigned char* xsrc_i[4];
#pragma unroll
    for (int i = 0; i < 4; ++i) {
        int rg = start + m0 + wave * 32 + 8 * i + (lane >> 3);
        if (rg > BATCH - 1) rg = BATCH - 1;
        xsrc_i[i] = xws + (size_t)rg * 8192 + (size_t)(lane & 7) * 16;
    }

#define STAGE_X(BUF, KT) do {                                                  \
    _Pragma("unroll")                                                          \
    for (int _i = 0; _i < 4; ++_i)                                             \
        __builtin_amdgcn_global_load_lds(                                      \
            (const __attribute__((address_space(1))) void*)(xsrc_i[_i] + (size_t)(KT) * 128), \
            (__attribute__((address_space(3))) void*)&Xs[BUF][(wave * 32 + 8 * _i) * 64], \
            16, 0, 0);                                                         \
} while (0)

    f32x4 acc[4][4];
#pragma unroll
    for (int i = 0; i < 4; ++i)
#pragma unroll
        for (int j = 0; j < 4; ++j) acc[i][j] = (f32x4){0.f, 0.f, 0.f, 0.f};

    // ---- prologue: W regs 2-deep, X tile 0 in flight ----
    float4 pwA[4], pwB[4];
#pragma unroll
    for (int j = 0; j < 4; ++j) pwA[j] = *(const float4*)(wsrc + 0 * 32 + j * 4);
#pragma unroll
    for (int j = 0; j < 4; ++j) pwB[j] = *(const float4*)(wsrc + 1 * 32 + j * 4);
    STAGE_X(0, 0);

    int kt = 0;

#define KSTEP(PW, CUR, NXT) do {                                               \
    { /* A: convert + ds_write W tile */                                       \
      uint4 h0, l0, h1, l1;                                                    \
      split_f4pair(PW[0], PW[1], h0, l0);                                      \
      split_f4pair(PW[2], PW[3], h1, l1);                                      \
      *(uint4*)&Wl[lidx(swr, 2 * wc)]         = h0;                            \
      *(uint4*)&Wl[lidx(swr, 2 * wc + 1)]     = h1;                            \
      *(uint4*)&Wl[lidx(swr, 4 + 2 * wc)]     = l0;                            \
      *(uint4*)&Wl[lidx(swr, 4 + 2 * wc + 1)] = l1; }                          \
    /* B: stage X(kt+1) into NXT (4 gload_lds) */                              \
    STAGE_X(NXT, (kt + 1) & 63);                                               \
    { /* C: W global loads for kt+2 */                                         \
      int _k2 = (kt + 2) & 63;                                                 \
      _Pragma("unroll")                                                        \
      for (int j = 0; j < 4; ++j)                                              \
          PW[j] = *(const float4*)(wsrc + _k2 * 32 + j * 4); }                 \
    /* D: X(kt) landed + W ds_writes visible; keep 8 vm-ops in flight */       \
    __builtin_amdgcn_sched_barrier(0);                                         \
    asm volatile("s_waitcnt vmcnt(8) lgkmcnt(0)" ::: "memory");                \
    __builtin_amdgcn_sched_barrier(0);                                         \
    __builtin_amdgcn_s_barrier();                                              \
    { /* E: fragment ds_reads */                                               \
      bf16x8 ah[4], al[4], bh[4], bl[4];                                       \
      _Pragma("unroll")                                                        \
      for (int mi = 0; mi < 4; ++mi) {                                         \
          int R = wm * 64 + mi * 16 + rl;                                      \
          ah[mi] = *(const bf16x8*)&Xs[CUR][lidx(R, g)];                       \
          al[mi] = *(const bf16x8*)&Xs[CUR][lidx(R, 4 + g)];                   \
      }                                                                        \
      _Pragma("unroll")                                                        \
      for (int ni = 0; ni < 4; ++ni) {                                         \
          int R = wn * 64 + ni * 16 + rl;                                      \
          bh[ni] = *(const bf16x8*)&Wl[lidx(R, g)];                            \
          bl[ni] = *(const bf16x8*)&Wl[lidx(R, 4 + g)];                        \
      }                                                                        \
      /* F: all reads done -> next ds_write safe after barrier */              \
      __builtin_amdgcn_sched_barrier(0);                                       \
      asm volatile("s_waitcnt lgkmcnt(0)" ::: "memory");                       \
      __builtin_amdgcn_sched_barrier(0);                                       \
      __builtin_amdgcn_s_barrier();                                            \
      /* G: 48 MFMA, product-major (dep distance 16) */                        \
      __builtin_amdgcn_s_setprio(1);                                           \
      _Pragma("unroll")                                                        \
      for (int mi = 0; mi < 4; ++mi)                                           \
          _Pragma("unroll")                                                    \
          for (int ni = 0; ni < 4; ++ni)                                       \
              acc[mi][ni] = __builtin_amdgcn_mfma_f32_16x16x32_bf16(ah[mi], bh[ni], acc[mi][ni], 0, 0, 0); \
      _Pragma("unroll")                                                        \
      for (int mi = 0; mi < 4; ++mi)                                           \
          _Pragma("unroll")                                                    \
          for (int ni = 0; ni < 4; ++ni)                                       \
              acc[mi][ni] = __builtin_amdgcn_mfma_f32_16x16x32_bf16(ah[mi], bl[ni], acc[mi][ni], 0, 0, 0); \
      _Pragma("unroll")                                                        \
      for (int mi = 0; mi < 4; ++mi)                                           \
          _Pragma("unroll")                                                    \
          for (int ni = 0; ni < 4; ++ni)                                       \
              acc[mi][ni] = __builtin_amdgcn_mfma_f32_16x16x32_bf16(al[mi], bh[ni], acc[mi][ni], 0, 0, 0); \
      __builtin_amdgcn_s_setprio(0); }                                         \
    ++kt;                                                                      \
} while (0)

#pragma unroll 1
    for (int it = 0; it < NKT / 2; ++it) {
        KSTEP(pwA, 0, 1);
        KSTEP(pwB, 1, 0);
    }
#undef KSTEP
#undef STAGE_X

    // ---- epilogue: bias add + scatter rows (mapping verified r3/r5) ----
    float bv[4];
#pragma unroll
    for (int ni = 0; ni < 4; ++ni)
        bv[ni] = bias[(size_t)e * DOUT + n0 + wn * 64 + ni * 16 + rl];
#pragma unroll
    for (int mi = 0; mi < 4; ++mi) {
#pragma unroll
        for (int j = 0; j < 4; ++j) {
            int rm = m0 + wm * 64 + mi * 16 + g * 4 + j;
            if (rm < cnt) {
                int s = sorted[start + rm];
                float* orow = out + (size_t)s * DOUT + n0 + wn * 64 + rl;
#pragma unroll
                for (int ni = 0; ni < 4; ++ni)
                    orow[ni * 16] = acc[mi][ni][j] + bv[ni];
            }
        }
    }
}

// --- Fallback GEMM (round-5 kernel, proven correct) used if ws too small ---
__global__ __launch_bounds__(256, 3)
void gemm_fb(const float* __restrict__ xs,
             const float* __restrict__ W,
             const float* __restrict__ bias,
             const int* __restrict__ offs,
             const int* __restrict__ sorted,
             float* __restrict__ out) {
    __shared__ __align__(16) unsigned short Xs[128 * 64];
    __shared__ __align__(16) unsigned short Ws[64 * 64];

    const int e = blockIdx.y;
    const int start = offs[e];
    const int cnt = offs[e + 1] - start;
    const int m0 = blockIdx.z * 128;
    if (m0 >= cnt) return;
    const int n0 = blockIdx.x * 64;

    const int tid = threadIdx.x;
    const int lane = tid & 63;
    const int wave = tid >> 6;
    const int wm = wave >> 1, wn = wave & 1;
    const int srow = tid & 127, kq = tid >> 7;
    const int swr = tid >> 2, wkq = tid & 3;

    const int rm_s = m0 + srow;
    const int xrow = (rm_s < cnt) ? sorted[start + rm_s] : -1;
    const float* xsrc = xs + (size_t)(xrow < 0 ? 0 : xrow) * DIN + kq * 16;
    const float* wsrc = W + ((size_t)e * DOUT + n0 + swr) * DIN + wkq * 8;

    f32x4 acc[4][2];
#pragma unroll
    for (int i = 0; i < 4; ++i)
#pragma unroll
        for (int j = 0; j < 2; ++j) acc[i][j] = (f32x4){0.f, 0.f, 0.f, 0.f};

    float4 px[4], pw[2];
#pragma unroll
    for (int j = 0; j < 4; ++j)
        px[j] = (xrow >= 0) ? *(const float4*)(xsrc + j * 4) : make_float4(0.f, 0.f, 0.f, 0.f);
    pw[0] = *(const float4*)(wsrc);
    pw[1] = *(const float4*)(wsrc + 4);

    for (int k0 = 0; k0 < DIN; k0 += 32) {
        {
            uint4 xh0, xl0, xh1, xl1, wh, wl;
            split_f4pair(px[0], px[1], xh0, xl0);
            split_f4pair(px[2], px[3], xh1, xl1);
            split_f4pair(pw[0], pw[1], wh, wl);
            *(uint4*)&Xs[lidx(srow, 2 * kq)]         = xh0;
            *(uint4*)&Xs[lidx(srow, 2 * kq + 1)]     = xh1;
            *(uint4*)&Xs[lidx(srow, 4 + 2 * kq)]     = xl0;
            *(uint4*)&Xs[lidx(srow, 4 + 2 * kq + 1)] = xl1;
            *(uint4*)&Ws[lidx(swr, wkq)]             = wh;
            *(uint4*)&Ws[lidx(swr, 4 + wkq)]         = wl;
        }
        __syncthreads();
        {
            int kn = (k0 + 32 < DIN) ? (k0 + 32) : 0;
#pragma unroll
            for (int j = 0; j < 4; ++j)
                px[j] = (xrow >= 0) ? *(const float4*)(xsrc + kn + j * 4) : make_float4(0.f, 0.f, 0.f, 0.f);
            pw[0] = *(const float4*)(wsrc + kn);
            pw[1] = *(const float4*)(wsrc + kn + 4);
        }
        {
            const int g = lane >> 4, rl = lane & 15;
            bf16x8 ah[4], al[4], bh[2], bl[2];
#pragma unroll
            for (int mi = 0; mi < 4; ++mi) {
                int R = wm * 64 + mi * 16 + rl;
                ah[mi] = *(const bf16x8*)&Xs[lidx(R, g)];
                al[mi] = *(const bf16x8*)&Xs[lidx(R, 4 + g)];
            }
#pragma unroll
            for (int ni = 0; ni < 2; ++ni) {
                int R = wn * 32 + ni * 16 + rl;
                bh[ni] = *(const bf16x8*)&Ws[lidx(R, g)];
                bl[ni] = *(const bf16x8*)&Ws[lidx(R, 4 + g)];
            }
#pragma unroll
            for (int mi = 0; mi < 4; ++mi)
#pragma unroll
                for (int ni = 0; ni < 2; ++ni)
                    acc[mi][ni] = __builtin_amdgcn_mfma_f32_16x16x32_bf16(ah[mi], bh[ni], acc[mi][ni], 0, 0, 0);
#pragma unroll
            for (int mi = 0; mi < 4; ++mi)
#pragma unroll
                for (int ni = 0; ni < 2; ++ni)
                    acc[mi][ni] = __builtin_amdgcn_mfma_f32_16x16x32_bf16(ah[mi], bl[ni], acc[mi][ni], 0, 0, 0);
#pragma unroll
            for (int mi = 0; mi < 4; ++mi)
#pragma unroll
                for (int ni = 0; ni < 2; ++ni)
                    acc[mi][ni] = __builtin_amdgcn_mfma_f32_16x16x32_bf16(al[mi], bh[ni], acc[mi][ni], 0, 0, 0);
        }
        __syncthreads();
    }

    const int g = lane >> 4, rl = lane & 15;
    float bv[2];
#pragma unroll
    for (int ni = 0; ni < 2; ++ni)
        bv[ni] = bias[(size_t)e * DOUT + n0 + wn * 32 + ni * 16 + rl];
#pragma unroll
    for (int mi = 0; mi < 4; ++mi) {
#pragma unroll
        for (int j = 0; j < 4; ++j) {
            int rm = m0 + wm * 64 + mi * 16 + g * 4 + j;
            if (rm < cnt) {
                int s = sorted[start + rm];
                float* orow = out + (size_t)s * DOUT + n0 + wn * 32 + rl;
#pragma unroll
                for (int ni = 0; ni < 2; ++ni)
                    orow[ni * 16] = acc[mi][ni][j] + bv[ni];
            }
        }
    }
}

extern "C" void kernel_launch(void* const* d_in, const int* in_sizes, int n_in,
                              void* d_out, int out_size, void* d_ws, size_t ws_size,
                              hipStream_t stream) {
    const float* xs      = (const float*)d_in[0];
    const float* mxs     = (const float*)d_in[1];
    const int*   actions = (const int*)d_in[2];
    const float* W       = (const float*)d_in[3];
    const float* b       = (const float*)d_in[4];
    float* out = (float*)d_out;

    int* ws_i   = (int*)d_ws;
    int* offs   = ws_i;         // NEXP+1
    int* sorted = ws_i + 32;    // BATCH

    sort_kernel<<<1, 1024, 0, stream>>>(actions, mxs,
                                        out + (size_t)BATCH * DOUT, offs, sorted);

    if (ws_size >= WS_X_OFF + WS_X_BYTES) {
        unsigned char* xws = (unsigned char*)d_ws + WS_X_OFF;
        xsplit_kernel<<<BATCH / 4, 256, 0, stream>>>(xs, sorted, offs, actions, xws);
        dim3 grid(DOUT / BN, NEXP, BATCH / BM);
        gemm_kernel<<<grid, 256, 0, stream>>>(xws, W, b, offs, sorted, out);
    } else {
        dim3 grid(DOUT / 64, NEXP, BATCH / 128);
        gemm_fb<<<grid, 256, 0, stream>>>(xs, W, b, offs, sorted, out);
    }
}